// Round 1
// baseline (60.393 us; speedup 1.0000x reference)
//
#include <hip/hip_runtime.h>
#include <hip/hip_bf16.h>

// Problem: out[b] = w_bias + sum_{s=0}^{S-1} w_weight[ text[s][b] ]
//   text: (S=200, B=2048) int32, values in [0, 50000)
//   w_weight: (1, V=50000) f32; w_bias: (1,) f32; out: (B, 1) f32
//
// Strategy: gather-reduce. Split S into 25 chunks of 8 so the 409600 random
// table gathers spread across 200 blocks (~200 CUs) instead of 8. Text loads
// are fully coalesced (256 consecutive b per wave-row). Partial sums combined
// with one float atomicAdd per thread (25 per output address). d_out is
// poisoned 0xAA before every timed call, so zero it with hipMemsetAsync
// (graph-capture safe) and fold bias into the sy==0 blocks.

#define VV 50000
#define SS 200
#define BB 2048
#define CHUNK 8   // s-values per thread; grid.y = SS/CHUNK = 25

__global__ __launch_bounds__(256) void MNB_455266533601_kernel(
    const int* __restrict__ text,
    const float* __restrict__ w,
    const float* __restrict__ bias,
    float* __restrict__ out)
{
    const int b  = blockIdx.x * 256 + threadIdx.x;  // grid.x = BB/256 = 8
    const int s0 = blockIdx.y * CHUNK;              // grid.y = 25

    float sum = 0.0f;
#pragma unroll
    for (int k = 0; k < CHUNK; ++k) {
        const int idx = text[(s0 + k) * BB + b];    // coalesced: 1KB/wave-row
        sum += w[idx];                              // random gather, L2-resident table
    }
    if (blockIdx.y == 0) sum += bias[0];
    atomicAdd(&out[b], sum);
}

extern "C" void kernel_launch(void* const* d_in, const int* in_sizes, int n_in,
                              void* d_out, int out_size, void* d_ws, size_t ws_size,
                              hipStream_t stream) {
    const int*   text = (const int*)  d_in[0];   // 409600 elements
    const float* w    = (const float*)d_in[1];   // 50000
    const float* bias = (const float*)d_in[2];   // 1
    float* out = (float*)d_out;                  // 2048

    // d_out is re-poisoned to 0xAA before every timed launch — must zero it.
    hipMemsetAsync(out, 0, (size_t)out_size * sizeof(float), stream);

    dim3 grid(BB / 256, SS / CHUNK, 1);  // (8, 25)
    dim3 block(256, 1, 1);
    MNB_455266533601_kernel<<<grid, block, 0, stream>>>(text, w, bias, out);
}